// Round 2
// baseline (789.975 us; speedup 1.0000x reference)
//
#include <hip/hip_runtime.h>

#define DIN 512
#define DH  64
#define BKT_SHIFT 10                // 1024 nodes per bucket
#define BKT_NODES 1024
#define MAXBKT 128                  // supports up to 131072 nodes
#define TILE 8192                   // edges per binning workgroup
#define SRC_BITS 17                 // n_nodes < 131072
#define SRC_MASK ((1u << SRC_BITS) - 1)

typedef __attribute__((ext_vector_type(8))) _Float16 half8_t;
typedef __attribute__((ext_vector_type(4))) float float4_t;

// ---- fused prep + bin (grid-partitioned):
//  block 0:    Wc=W2@Wlin -> Wct fp16, bias_out=b2@Wlin+blin
//  blocks 1-4: Wt fp16 [n][k] = W1^T slice via LDS transpose
//  blocks 5+:  bin tile (blockIdx.x-5) of edges into fixed-cap bucket regions
__global__ __launch_bounds__(256) void k_prepbin(const float* __restrict__ W1,
                                                 const float* __restrict__ W2,
                                                 const float* __restrict__ b2,
                                                 const float* __restrict__ Wlin,
                                                 const float* __restrict__ blin,
                                                 _Float16* __restrict__ Wt,
                                                 _Float16* __restrict__ Wct,
                                                 float* __restrict__ bias_out,
                                                 const int* __restrict__ src,
                                                 const int* __restrict__ dst,
                                                 int n_edges,
                                                 int* __restrict__ gcur,
                                                 unsigned int* __restrict__ tmp,
                                                 int nbkt, int cap) {
  const int tid = threadIdx.x;
  if (blockIdx.x == 0) {
    __shared__ float WcS[64 * 64];
    for (int idx = tid; idx < 64 * 64; idx += 256) {
      int i = idx >> 6, j = idx & 63;
      float s = 0.f;
      #pragma unroll 8
      for (int k = 0; k < 64; ++k) s = fmaf(W2[i * 64 + k], Wlin[k * 64 + j], s);
      WcS[idx] = s;
    }
    if (tid < 64) {
      float s = blin[tid];
      #pragma unroll 8
      for (int k = 0; k < 64; ++k) s = fmaf(b2[k], Wlin[k * 64 + tid], s);
      bias_out[tid] = s;
    }
    __syncthreads();
    for (int G = tid; G < 64 * 64 / 8; G += 256) {
      int n = G >> 3, k = (G & 7) * 8;
      half8_t h;
      #pragma unroll
      for (int j = 0; j < 8; ++j) h[j] = (_Float16)WcS[(k + j) * 64 + n];
      *(half8_t*)&Wct[(size_t)n * 64 + k] = h;
    }
  } else if (blockIdx.x <= 4) {
    __shared__ _Float16 T[64][136];
    const int k0 = (blockIdx.x - 1) * 128;
    for (int idx = tid; idx < 128 * 64; idx += 256) {
      int kk = idx >> 6, n = idx & 63;
      T[n][kk] = (_Float16)W1[(size_t)(k0 + kk) * 64 + n];
    }
    __syncthreads();
    for (int G = tid; G < 64 * 16; G += 256) {
      int n = G >> 4, g = (G & 15) * 8;
      half8_t h = *(const half8_t*)&T[n][g];
      *(half8_t*)&Wt[(size_t)n * 512 + k0 + g] = h;
    }
  } else {
    __shared__ int cnt[MAXBKT];
    __shared__ int base[MAXBKT];
    for (int b = tid; b < nbkt; b += 256) cnt[b] = 0;
    __syncthreads();
    int e0 = (blockIdx.x - 5) * TILE;
    int e1 = min(e0 + TILE, n_edges);
    for (int e = e0 + tid; e < e1; e += 256)
      atomicAdd(&cnt[dst[e] >> BKT_SHIFT], 1);
    __syncthreads();
    for (int b = tid; b < nbkt; b += 256) {
      int c = cnt[b];
      base[b] = c ? (b * cap + atomicAdd(&gcur[b], c)) : 0;
      cnt[b] = 0;
    }
    __syncthreads();
    for (int e = e0 + tid; e < e1; e += 256) {
      int d = dst[e];
      int bkt = d >> BKT_SHIFT;
      int off = atomicAdd(&cnt[bkt], 1);
      int pos = base[bkt] + off;
      if (pos < (bkt + 1) * cap)  // overflow guard (never hit for random dst)
        tmp[pos] = (unsigned int)src[e] |
                   ((unsigned int)(d & (BKT_NODES - 1)) << SRC_BITS);
    }
  }
}

// ------- per-bucket: degrees -> rowbeg/rowcnt/dinv, then place srcs (4B) ------
__global__ __launch_bounds__(256) void k_place(const unsigned int* __restrict__ tmp,
                                               const int* __restrict__ gcur,
                                               int* __restrict__ rowbeg,
                                               int* __restrict__ rowcnt,
                                               float* __restrict__ dinv,
                                               int* __restrict__ srcs,
                                               int n_nodes, int cap) {
  __shared__ int cnt[BKT_NODES];
  __shared__ int sh[256];
  const int t = threadIdx.x;
  const int bkt = blockIdx.x;
  #pragma unroll
  for (int k = 0; k < BKT_NODES / 256; ++k) cnt[t + 256 * k] = 0;
  __syncthreads();
  const int beg = bkt * cap;
  const int end = beg + min(gcur[bkt], cap);
  for (int j = beg + t; j < end; j += 256)
    atomicAdd(&cnt[tmp[j] >> SRC_BITS], 1);
  __syncthreads();
  int v[4];
  int s = 0;
  const int base = t * 4;
  #pragma unroll
  for (int k = 0; k < 4; ++k) {
    v[k] = cnt[base + k];
    s += v[k];
  }
  sh[t] = s;
  __syncthreads();
  for (int off = 1; off < 256; off <<= 1) {
    int x = sh[t];
    int y = (t >= off) ? sh[t - off] : 0;
    __syncthreads();
    sh[t] = x + y;
    __syncthreads();
  }
  int excl = sh[t] - s;
  #pragma unroll
  for (int k = 0; k < 4; ++k) {
    int idx = base + k;
    int node = (bkt << BKT_SHIFT) + idx;
    if (node < n_nodes) {
      rowbeg[node] = beg + excl;
      rowcnt[node] = v[k];
      dinv[node] = rsqrtf((float)(v[k] + 1));   // +1 self loop
    }
    cnt[idx] = excl;
    excl += v[k];
  }
  __syncthreads();
  for (int j = beg + t; j < end; j += 256) {
    unsigned int e = tmp[j];
    int r = e >> SRC_BITS;
    int pos = atomicAdd(&cnt[r], 1);
    srcs[beg + pos] = (int)(e & SRC_MASK);
  }
}

// ---- MFMA fp16 GEMM + row scaling: Ch[p][r,:16] = (fp16)( (A[r,:] @ Bt^T) * dinv[r] )
// Output is written in PASS-SPLIT layout: 4 sub-arrays of [M][16] halves so that
// the gather's per-pass working set (3.2 MB) fits a per-XCD L2 (4 MiB).
// 1024 threads = 16 waves, 256 rows/block. Bt [64][KDIM] fp16, LDS-swizzled.
// NOTE: A-operand row index = lane&15, but C/D output row = (lane>>4)*4 + reg.
// dinv must be indexed by the OUTPUT row (bug fixed in R11).
template <int KDIM, bool A_HALF>
__global__ __launch_bounds__(1024) void k_mfma(const void* __restrict__ Ain,
                                               const _Float16* __restrict__ Bt,
                                               const float* __restrict__ dinv,
                                               _Float16* __restrict__ Ch, int M) {
  constexpr int BS_HALVES = (64 * KDIM > 16384) ? 64 * KDIM : 16384;
  __shared__ _Float16 Bs[BS_HALVES];  // 64KB (K=512) / 32KB (K=64)
  const int tid = threadIdx.x;
  for (int G = tid; G < 8 * KDIM; G += 1024) {
    int n = G / (KDIM / 8);
    int g = G % (KDIM / 8);
    half8_t h = *(const half8_t*)&Bt[(size_t)G * 8];
    *(half8_t*)&Bs[n * KDIM + ((g ^ (n & 7)) * 8)] = h;
  }
  __syncthreads();

  const int wave = tid >> 6, lane = tid & 63;
  const int quad = lane >> 4, lrow = lane & 15;
  const int row = blockIdx.x * 256 + wave * 16 + lrow;
  const int rowc = min(row, M - 1);

  float4_t acc[4] = {{0.f, 0.f, 0.f, 0.f}, {0.f, 0.f, 0.f, 0.f},
                     {0.f, 0.f, 0.f, 0.f}, {0.f, 0.f, 0.f, 0.f}};

  #pragma unroll
  for (int k0 = 0; k0 < KDIM; k0 += 32) {
    half8_t a;
    if (A_HALF) {
      a = *(const half8_t*)((const _Float16*)Ain + (size_t)rowc * KDIM + k0 + quad * 8);
    } else {
      const float* Af = (const float*)Ain + (size_t)rowc * KDIM + k0 + quad * 8;
      float4 x0 = *(const float4*)Af;
      float4 x1 = *(const float4*)(Af + 4);
      a[0] = (_Float16)x0.x; a[1] = (_Float16)x0.y;
      a[2] = (_Float16)x0.z; a[3] = (_Float16)x0.w;
      a[4] = (_Float16)x1.x; a[5] = (_Float16)x1.y;
      a[6] = (_Float16)x1.z; a[7] = (_Float16)x1.w;
    }
    const int g = (k0 >> 3) + quad;
    #pragma unroll
    for (int nb = 0; nb < 4; ++nb) {
      int n = nb * 16 + lrow;
      half8_t b = *(const half8_t*)&Bs[n * KDIM + ((g ^ (n & 7)) * 8)];
      acc[nb] = __builtin_amdgcn_mfma_f32_16x16x32_f16(a, b, acc[nb], 0, 0, 0);
    }
  }

  // per-OUTPUT-row dinv (output row = wave*16 + quad*4 + r)
  const int orow_base = blockIdx.x * 256 + wave * 16 + quad * 4;
  float dnr[4];
  #pragma unroll
  for (int r = 0; r < 4; ++r) dnr[r] = dinv[min(orow_base + r, M - 1)];

  __syncthreads();
  _Float16* scratch = Bs + wave * 1024;  // 16x64 halves per wave
  #pragma unroll
  for (int nb = 0; nb < 4; ++nb)
    #pragma unroll
    for (int r = 0; r < 4; ++r)
      scratch[(quad * 4 + r) * 64 + nb * 16 + lrow] = (_Float16)(acc[nb][r] * dnr[r]);
  const int r2 = lane >> 2, c2 = (lane & 3) * 16;
  const int row_out = blockIdx.x * 256 + wave * 16 + r2;
  half8_t o0 = *(const half8_t*)&scratch[r2 * 64 + c2];
  half8_t o1 = *(const half8_t*)&scratch[r2 * 64 + c2 + 8];
  if (row_out < M) {
    // pass-split store: channels [c2, c2+16) live in pass p = c2>>4
    _Float16* d0 = Ch + ((size_t)(c2 >> 4) * M + row_out) * 16;
    *(half8_t*)d0 = o0;
    *(half8_t*)(d0 + 8) = o1;
  }
}

// ---- per-node-wave CSR gather over pre-scaled rows fs = h*dinv ---------------
// 4 channel-split passes (blockIdx.y = pass): per-pass table is [N][16] halves
// = 3.2 MB, L2-resident per XCD. Lane = 32 edge slots x 2 channel groups.
// out = act( dinv[n]*( sum_e fs[s_e,:] + fs[n,:] ) + bias )
__global__ __launch_bounds__(256) void k_gather(const _Float16* __restrict__ fs,
                                                const int* __restrict__ rowbeg,
                                                const int* __restrict__ rowcnt,
                                                const int* __restrict__ srcs,
                                                const float* __restrict__ dinv,
                                                const float* __restrict__ bias,
                                                _Float16* __restrict__ outh,
                                                float* __restrict__ outf,
                                                int n_nodes) {
  int node = blockIdx.x * 4 + (threadIdx.x >> 6);
  int lane = threadIdx.x & 63;
  if (node >= n_nodes) return;
  const int pass = blockIdx.y;
  const int esub = lane >> 1;       // 0..31 edge slot
  const int cg = (lane & 1) * 8;    // channel group base within the 16-ch pass
  const _Float16* ft = fs + (size_t)pass * n_nodes * 16;
  const int beg = rowbeg[node];
  const int end = beg + rowcnt[node];
  float acc[8] = {0.f, 0.f, 0.f, 0.f, 0.f, 0.f, 0.f, 0.f};
  int j = beg;
  for (; j + 64 <= end; j += 64) {
    int s0 = srcs[j + esub];
    int s1 = srcs[j + 32 + esub];
    half8_t f0 = *(const half8_t*)&ft[(size_t)s0 * 16 + cg];
    half8_t f1 = *(const half8_t*)&ft[(size_t)s1 * 16 + cg];
    #pragma unroll
    for (int k = 0; k < 8; ++k) acc[k] += (float)f0[k];
    #pragma unroll
    for (int k = 0; k < 8; ++k) acc[k] += (float)f1[k];
  }
  for (; j < end; j += 32) {
    int idx = j + esub;
    bool act = idx < end;
    int s = srcs[act ? idx : beg];
    float w = act ? 1.f : 0.f;
    half8_t f = *(const half8_t*)&ft[(size_t)s * 16 + cg];
    #pragma unroll
    for (int k = 0; k < 8; ++k) acc[k] = fmaf((float)f[k], w, acc[k]);
  }
  // reduce across the 32 edge slots (lane bits 1..5)
  #pragma unroll
  for (int m = 2; m <= 32; m <<= 1)
    #pragma unroll
    for (int k = 0; k < 8; ++k) acc[k] += __shfl_xor(acc[k], m, 64);
  if (esub == 0) {                  // lanes 0 and 1
    float dn = dinv[node];
    half8_t sf = *(const half8_t*)&ft[(size_t)node * 16 + cg];
    float v[8];
    #pragma unroll
    for (int k = 0; k < 8; ++k)
      v[k] = fmaf(acc[k] + (float)sf[k], dn, bias[pass * 16 + cg + k]);
    if (outh) {
      half8_t o;
      #pragma unroll
      for (int k = 0; k < 8; ++k) o[k] = (_Float16)fmaxf(v[k], 0.f);
      *(half8_t*)&outh[(size_t)node * 64 + pass * 16 + cg] = o;
    } else {
      float4 o0 = make_float4(v[0], v[1], v[2], v[3]);
      float4 o1 = make_float4(v[4], v[5], v[6], v[7]);
      *(float4*)&outf[(size_t)node * 64 + pass * 16 + cg] = o0;
      *(float4*)&outf[(size_t)node * 64 + pass * 16 + cg + 4] = o1;
    }
  }
}

extern "C" void kernel_launch(void* const* d_in, const int* in_sizes, int n_in,
                              void* d_out, int out_size, void* d_ws, size_t ws_size,
                              hipStream_t stream) {
  const float* x    = (const float*)d_in[0];
  const int*   ei   = (const int*)d_in[1];
  const float* W1   = (const float*)d_in[2];
  const float* b1   = (const float*)d_in[3];
  const float* W2   = (const float*)d_in[4];
  const float* b2   = (const float*)d_in[5];
  const float* Wlin = (const float*)d_in[6];
  const float* blin = (const float*)d_in[7];
  float* out = (float*)d_out;

  const int n_nodes = in_sizes[0] / DIN;
  const int n_edges = in_sizes[1] / 2;
  const int* src = ei;
  const int* dst = ei + n_edges;
  const int nbkt = (n_nodes + BKT_NODES - 1) >> BKT_SHIFT;
  const int ntiles = (n_edges + TILE - 1) / TILE;
  const int cap = ((n_edges / nbkt) * 5 / 4 + 1024 + 255) & ~255;  // bucket capacity

  char* ws = (char*)d_ws;
  size_t off = 0;
  auto alloc = [&](size_t bytes) {
    void* p = ws + off;
    off += (bytes + 255) & ~(size_t)255;
    return p;
  };
  const size_t featH = (size_t)n_nodes * DH * 2;
  const size_t padE = (size_t)nbkt * cap;
  _Float16*     fs1      = (_Float16*)alloc(featH);   // (x@W1)*dinv fp16, [4][N][16]
  _Float16*     h1r      = (_Float16*)alloc(featH);   // relu'd layer-1 out, fp16 [N][64]
  _Float16*     fs2      = (_Float16*)alloc(featH);   // (h1r@Wc)*dinv fp16, [4][N][16]
  unsigned int* tmp      = (unsigned int*)alloc(padE * 4);
  int*          srcs     = (int*)alloc(padE * 4);
  float*        dinv     = (float*)alloc((size_t)n_nodes * 4);
  int*          rowbeg   = (int*)alloc((size_t)n_nodes * 4);
  int*          rowcnt   = (int*)alloc((size_t)n_nodes * 4);
  int*          gcur     = (int*)alloc((size_t)MAXBKT * 4);
  _Float16*     Wt       = (_Float16*)alloc(64 * 512 * 2);
  _Float16*     Wct      = (_Float16*)alloc(64 * 64 * 2);
  float*        bias_out = (float*)alloc(64 * 4);

  hipMemsetAsync(gcur, 0, (size_t)nbkt * 4, stream);

  k_prepbin<<<5 + ntiles, 256, 0, stream>>>(W1, W2, b2, Wlin, blin, Wt, Wct,
                                            bias_out, src, dst, n_edges, gcur,
                                            tmp, nbkt, cap);
  k_place<<<nbkt, 256, 0, stream>>>(tmp, gcur, rowbeg, rowcnt, dinv, srcs,
                                    n_nodes, cap);

  const int mblocks = (n_nodes + 255) / 256;
  const dim3 gg((n_nodes + 3) / 4, 4);   // .y = channel-split pass

  // layer 1: fs1 = (x@W1)*dinv (fp16 MFMA, split layout), gather -> h1r (ReLU)
  k_mfma<512, false><<<mblocks, 1024, 0, stream>>>(x, Wt, dinv, fs1, n_nodes);
  k_gather<<<gg, 256, 0, stream>>>(fs1, rowbeg, rowcnt, srcs, dinv, b1,
                                   h1r, nullptr, n_nodes);

  // layer 2 (+ folded final linear): fs2 = (h1r@Wc)*dinv, gather -> out (fp32)
  k_mfma<64, true><<<mblocks, 1024, 0, stream>>>(h1r, Wct, dinv, fs2, n_nodes);
  k_gather<<<gg, 256, 0, stream>>>(fs2, rowbeg, rowcnt, srcs, dinv,
                                   bias_out, nullptr, out, n_nodes);
}